// Round 5
// baseline (1018.082 us; speedup 1.0000x reference)
//
#include <hip/hip_runtime.h>
#include <hip/hip_bf16.h>
#include <math.h>

#define NN   16384
#define EE   65536
#define DD   512
#define HH   4
#define FINN 7

typedef __attribute__((ext_vector_type(4))) float  floatx4;
typedef __attribute__((ext_vector_type(8))) short  shortx8;
typedef __attribute__((ext_vector_type(8))) unsigned short ushortx8;

// ---------------- helpers ----------------
__device__ inline float bf2f(unsigned short u) {
  return __uint_as_float(((unsigned)u) << 16);
}
__device__ inline unsigned short f2bf(float f) {
  unsigned u = __float_as_uint(f);
  unsigned r = (u + 0x7fffu + ((u >> 16) & 1u)) >> 16;
  return (unsigned short)r;
}
__device__ inline float wave_reduce_sum(float v) {
  #pragma unroll
  for (int off = 32; off > 0; off >>= 1) v += __shfl_down(v, off, 64);
  return v;
}
__device__ inline float wave_allreduce_sum(float v) {
  #pragma unroll
  for (int off = 32; off > 0; off >>= 1) v += __shfl_xor(v, off, 64);
  return v;
}
__device__ inline float half_allreduce_sum(float v) {  // reduce within 32-lane halves
  #pragma unroll
  for (int off = 16; off > 0; off >>= 1) v += __shfl_xor(v, off, 64);
  return v;
}
__device__ inline void async16(const unsigned short* g, unsigned short* l) {
  __builtin_amdgcn_global_load_lds(
      (const __attribute__((address_space(1))) void*)g,
      (__attribute__((address_space(3))) void*)l, 16, 0, 0);
}

// ---------------- CSR build ----------------
__global__ void k_count(const int* __restrict__ dst, int* __restrict__ cnt) {
  int e = blockIdx.x * 256 + threadIdx.x;
  if (e < EE) atomicAdd(&cnt[dst[e]], 1);
}

__global__ void k_scan(const int* __restrict__ cnt, int* __restrict__ offs) {
  __shared__ int sums[256];
  int t = threadIdx.x;
  const int chunk = NN / 256;
  int base = t * chunk;
  int s = 0;
  for (int i = 0; i < chunk; ++i) s += cnt[base + i];
  sums[t] = s;
  __syncthreads();
  for (int off = 1; off < 256; off <<= 1) {
    int v = (t >= off) ? sums[t - off] : 0;
    __syncthreads();
    sums[t] += v;
    __syncthreads();
  }
  int run = (t == 0) ? 0 : sums[t - 1];
  for (int i = 0; i < chunk; ++i) {
    offs[base + i] = run;
    run += cnt[base + i];
  }
  if (t == 255) offs[NN] = run;
}

__global__ void k_fill(const int* __restrict__ dst, const int* __restrict__ offs,
                       int* __restrict__ cursor, int* __restrict__ eids) {
  int e = blockIdx.x * 256 + threadIdx.x;
  if (e >= EE) return;
  int d = dst[e];
  int p = offs[d] + atomicAdd(&cursor[d], 1);
  eids[p] = e;
}

// ---------------- edge_attr mean ----------------
__global__ void k_edge_mean(const float* __restrict__ eattr, float* __restrict__ macc) {
  int tid = blockIdx.x * blockDim.x + threadIdx.x;
  int stride = gridDim.x * blockDim.x;
  float ax = 0.f, ay = 0.f, az = 0.f, aw = 0.f;
  for (int e = tid; e < EE; e += stride) {
    float4 v = ((const float4*)eattr)[e];
    ax += v.x; ay += v.y; az += v.z; aw += v.w;
  }
  ax = wave_reduce_sum(ax); ay = wave_reduce_sum(ay);
  az = wave_reduce_sum(az); aw = wave_reduce_sum(aw);
  if ((threadIdx.x & 63) == 0) {
    atomicAdd(&macc[0], ax); atomicAdd(&macc[1], ay);
    atomicAdd(&macc[2], az); atomicAdd(&macc[3], aw);
  }
}

// ------------- weight transpose+cast: W slice (K x N, ld) f32 -> Wt[N][K] bf16 -------
__global__ void k_transcast(const float* __restrict__ W, int ld,
                            unsigned short* __restrict__ Wt, int K, int N) {
  __shared__ float tile[32][33];
  int bx = blockIdx.x;
  int by = blockIdx.y;
  int tx = threadIdx.x & 31, ty = threadIdx.x >> 5;
  #pragma unroll
  for (int i = 0; i < 32; i += 8)
    tile[ty + i][tx] = W[(size_t)(by * 32 + ty + i) * ld + bx * 32 + tx];
  __syncthreads();
  #pragma unroll
  for (int i = 0; i < 32; i += 8)
    Wt[(size_t)(bx * 32 + ty + i) * K + by * 32 + tx] = f2bf(tile[tx][ty + i]);
}

// ------------- combined GAT bias ----------------
__global__ void k_bcomb(const float* __restrict__ bl, const float* __restrict__ br,
                        float* __restrict__ bc0, float* __restrict__ bc1) {
  int i = blockIdx.x * 256 + threadIdx.x;
  if (i >= 4096) return;
  int b = i >> 11, c = i & 2047;
  float v = (c < 1024) ? bl[b * 1024 + c] : br[b * 1024 + c - 1024];
  (b ? bc1 : bc0)[c] = v;
}

// ---------------- input projection ----------------
__global__ void k_proj(const float* __restrict__ x, const float* __restrict__ W,
                       const float* __restrict__ b, unsigned short* __restrict__ hbf) {
  int gid = blockIdx.x * 256 + threadIdx.x;
  if (gid >= NN * DD) return;
  int n = gid >> 9, d = gid & 511;
  const float* xr = x + n * FINN;
  float acc = b[d];
  #pragma unroll
  for (int k = 0; k < FINN; ++k) acc = fmaf(xr[k], W[k * DD + d], acc);
  hbf[gid] = f2bf(fmaxf(acc, 0.f));
}

// ---------------- bf16 MFMA GEMM with XOR-swizzled LDS ----------------
__global__ __launch_bounds__(256) void k_bgemm(
    const unsigned short* __restrict__ A, const unsigned short* __restrict__ Bt,
    const float* __restrict__ bias, void* __restrict__ Cout,
    int M, int Nc, int K, int act, int outbf) {
  __shared__ unsigned short As[128 * 64];
  __shared__ unsigned short Bs[128 * 64];
  const int tid = threadIdx.x;
  const int wv = tid >> 6;
  const int lane = tid & 63;
  const int row0 = blockIdx.y * 128;
  const int col0 = blockIdx.x * 128;
  const int wrow = (wv & 1) * 64;
  const int wcol = (wv >> 1) * 64;

  floatx4 acc[4][4];
  #pragma unroll
  for (int r = 0; r < 4; ++r)
    #pragma unroll
    for (int c = 0; c < 4; ++c)
      #pragma unroll
      for (int q = 0; q < 4; ++q) acc[r][c][q] = 0.f;

  const unsigned short* Ab = A + (size_t)row0 * K;
  const unsigned short* Bb = Bt + (size_t)col0 * K;
  const int lrow = lane >> 3;                       // 0..7 within segment
  const int lchunk = (lane & 7) ^ lrow;             // swizzled source k-chunk
  const int lk = lchunk * 8;                        // shorts

  const int frow = lane & 15;
  const int fx = lane >> 4;
  const int fsw = lane & 7;

  for (int k0 = 0; k0 < K; k0 += 64) {
    #pragma unroll
    for (int i = 0; i < 4; ++i) {
      int seg = i * 4 + wv;
      int r = seg * 8 + lrow;
      async16(Ab + (size_t)r * K + k0 + lk, &As[seg * 512]);
      async16(Bb + (size_t)r * K + k0 + lk, &Bs[seg * 512]);
    }
    __syncthreads();
    #pragma unroll
    for (int s = 0; s < 2; ++s) {
      int ch = ((s * 4 + fx) ^ fsw) * 8;
      shortx8 af[4], bfr[4];
      #pragma unroll
      for (int r = 0; r < 4; ++r)
        af[r] = *(const shortx8*)&As[(wrow + r * 16 + frow) * 64 + ch];
      #pragma unroll
      for (int c = 0; c < 4; ++c)
        bfr[c] = *(const shortx8*)&Bs[(wcol + c * 16 + frow) * 64 + ch];
      #pragma unroll
      for (int r = 0; r < 4; ++r)
        #pragma unroll
        for (int c = 0; c < 4; ++c)
          acc[r][c] = __builtin_amdgcn_mfma_f32_16x16x32_bf16(af[r], bfr[c], acc[r][c], 0, 0, 0);
    }
    __syncthreads();
  }

  #pragma unroll
  for (int r = 0; r < 4; ++r) {
    int rowb = row0 + wrow + r * 16 + (lane >> 4) * 4;
    #pragma unroll
    for (int c = 0; c < 4; ++c) {
      int col = col0 + wcol + c * 16 + (lane & 15);
      float bv = bias ? bias[col] : 0.f;
      #pragma unroll
      for (int q = 0; q < 4; ++q) {
        float v = acc[r][c][q] + bv;
        if (act) v = fmaxf(v, 0.f);
        if (outbf)
          ((unsigned short*)Cout)[(size_t)(rowb + q) * Nc + col] = f2bf(v);
        else
          ((float*)Cout)[(size_t)(rowb + q) * Nc + col] = v;
      }
    }
  }
}

// ------------- GINE aggregate ----------------
__global__ void k_gine_agg(const unsigned short* __restrict__ hbf,
                           const int* __restrict__ src, const float* __restrict__ eattr,
                           const float* __restrict__ geW, const float* __restrict__ geb,
                           const int* __restrict__ offs, const int* __restrict__ eids,
                           unsigned short* __restrict__ gbf) {
  int wave = (blockIdx.x * blockDim.x + threadIdx.x) >> 6;
  int lane = threadIdx.x & 63;
  if (wave >= NN) return;
  int n = wave;
  int cbase = lane * 8;
  float w[4][8], bb[8];
  #pragma unroll
  for (int j = 0; j < 8; ++j) bb[j] = geb[cbase + j];
  #pragma unroll
  for (int k = 0; k < 4; ++k)
    #pragma unroll
    for (int j = 0; j < 8; ++j) w[k][j] = geW[k * DD + cbase + j];
  float acc[8] = {0.f};
  int beg = offs[n], end = offs[n + 1];
  int ecur = (beg < end) ? eids[beg] : 0;
  int scur = (beg < end) ? src[ecur] : 0;
  for (int p = beg; p < end; ++p) {
    int e = ecur, s = scur;
    if (p + 1 < end) { ecur = eids[p + 1]; scur = src[ecur]; }
    float4 ea = ((const float4*)eattr)[e];
    ushortx8 hv = *(const ushortx8*)(hbf + (size_t)s * DD + cbase);
    #pragma unroll
    for (int j = 0; j < 8; ++j) {
      float ev = bb[j];
      ev = fmaf(ea.x, w[0][j], ev);
      ev = fmaf(ea.y, w[1][j], ev);
      ev = fmaf(ea.z, w[2][j], ev);
      ev = fmaf(ea.w, w[3][j], ev);
      acc[j] += fmaxf(bf2f(hv[j]) + ev, 0.f);
    }
  }
  ushortx8 hn = *(const ushortx8*)(hbf + (size_t)n * DD + cbase);
  ushortx8 o;
  #pragma unroll
  for (int j = 0; j < 8; ++j) o[j] = f2bf(bf2f(hn[j]) + acc[j]);
  *(ushortx8*)(gbf + (size_t)n * DD + cbase) = o;
}

// -------- layer-0 LayerNorm ----------------
__global__ void k_ln0(const float* __restrict__ g, const unsigned short* __restrict__ res,
                      const float* __restrict__ gamma, const float* __restrict__ beta,
                      unsigned short* __restrict__ obf) {
  int wave = (blockIdx.x * blockDim.x + threadIdx.x) >> 6;
  int lane = threadIdx.x & 63;
  if (wave >= NN) return;
  int n = wave;
  int cbase = lane * 8;
  const float4* g4 = (const float4*)(g + (size_t)n * DD + cbase);
  ushortx8 rv = *(const ushortx8*)(res + (size_t)n * DD + cbase);
  float4 ga = g4[0], gb = g4[1];
  float v[8] = {ga.x, ga.y, ga.z, ga.w, gb.x, gb.y, gb.z, gb.w};
  float s = 0.f, sq = 0.f;
  #pragma unroll
  for (int j = 0; j < 8; ++j) {
    float t = fmaxf(v[j], 0.f) + bf2f(rv[j]);
    v[j] = t;
    s += t; sq += t * t;
  }
  s = wave_allreduce_sum(s);
  sq = wave_allreduce_sum(sq);
  float mu = s * (1.f / DD);
  float var = sq * (1.f / DD) - mu * mu;
  float rstd = rsqrtf(var + 1e-5f);
  ushortx8 ob;
  #pragma unroll
  for (int j = 0; j < 8; ++j)
    ob[j] = f2bf(fmaf((v[j] - mu) * rstd, gamma[cbase + j], beta[cbase + j]));
  *(ushortx8*)(obf + (size_t)n * DD + cbase) = ob;
}

// ======== fused GATv2: logits + softmax + aggregate (+LN on batch 1) ========
// wave per node; 2 heads per batch (half-wave per head, 16 cols per lane).
// Direct exp (no max subtraction): logits are O(+-10), f32 exp is safe, and the
// softmax ratio is mathematically identical. This keeps every edge iteration
// independent -> full ILP (the r4 online-softmax carried chain was the 225us bug).
__global__ void k_gat_fused(const unsigned short* __restrict__ xlr,
                            const int* __restrict__ src,
                            const int* __restrict__ offs, const int* __restrict__ eids,
                            const float* __restrict__ eattr, const float* __restrict__ macc,
                            const float* __restrict__ geW /*4x2048*/,
                            const float* __restrict__ att /*4x512*/,
                            float* __restrict__ B, unsigned short* __restrict__ Xbf,
                            const float* __restrict__ gbias,
                            const float* __restrict__ gamma, const float* __restrict__ beta,
                            int batch) {
  int wave = (blockIdx.x * blockDim.x + threadIdx.x) >> 6;
  int lane = threadIdx.x & 63;
  if (wave >= NN) return;
  int n = wave;
  int half = lane >> 5;
  int li = lane & 31;
  int cb = li * 16;
  int hc = (2 * batch + half) * 512 + cb;

  float w[4][16], at[16];
  #pragma unroll
  for (int k = 0; k < 4; ++k)
    #pragma unroll
    for (int j = 0; j < 16; ++j) w[k][j] = geW[k * (HH * DD) + hc + j];
  #pragma unroll
  for (int j = 0; j < 16; ++j) at[j] = att[hc + j];

  // xr row for this node (target transform), kept in registers
  float xrv[16];
  {
    const unsigned short* rp = xlr + (size_t)n * 2048 + 1024 + half * 512 + cb;
    ushortx8 r0 = *(const ushortx8*)rp, r1 = *(const ushortx8*)(rp + 8);
    #pragma unroll
    for (int j = 0; j < 8; ++j) { xrv[j] = bf2f(r0[j]); xrv[j + 8] = bf2f(r1[j]); }
  }
  const float invE = 1.f / EE;
  float mea[4] = {macc[0] * invE, macc[1] * invE, macc[2] * invE, macc[3] * invE};

  float l = 0.f;
  float acc[16];
  #pragma unroll
  for (int j = 0; j < 16; ++j) acc[j] = 0.f;

  int beg = offs[n], end = offs[n + 1];

  // software-pipelined: row registers for iteration i loaded during i-1.
  // iteration p = beg-1 is the self-loop.
  ushortx8 c0, c1;          // current row (xl part)
  float4 eac;               // current edge attr
  {
    const unsigned short* xs = xlr + (size_t)n * 2048 + half * 512 + cb;
    c0 = *(const ushortx8*)xs;
    c1 = *(const ushortx8*)(xs + 8);
    eac = make_float4(mea[0], mea[1], mea[2], mea[3]);
  }
  int enext = (beg < end) ? eids[beg] : 0;
  int snext = (beg < end) ? src[enext] : 0;

  for (int p = beg - 1; p < end; ++p) {
    // issue next row load before processing current
    ushortx8 n0 = c0, n1 = c1;
    float4 ean = eac;
    if (p + 1 < end) {
      const unsigned short* xs = xlr + (size_t)snext * 2048 + half * 512 + cb;
      n0 = *(const ushortx8*)xs;
      n1 = *(const ushortx8*)(xs + 8);
      ean = ((const float4*)eattr)[enext];
      int pn = p + 2;
      if (pn < end) { enext = eids[pn]; snext = src[enext]; }
    }
    // process current
    float xlv[16];
    #pragma unroll
    for (int j = 0; j < 8; ++j) { xlv[j] = bf2f(c0[j]); xlv[j + 8] = bf2f(c1[j]); }
    float zacc = 0.f;
    #pragma unroll
    for (int j = 0; j < 16; ++j) {
      float z = xlv[j] + xrv[j];
      z = fmaf(eac.x, w[0][j], z);
      z = fmaf(eac.y, w[1][j], z);
      z = fmaf(eac.z, w[2][j], z);
      z = fmaf(eac.w, w[3][j], z);
      z = (z >= 0.f) ? z : 0.2f * z;
      zacc = fmaf(z, at[j], zacc);
    }
    float L = half_allreduce_sum(zacc);
    float wgt = __expf(L);
    l += wgt;
    #pragma unroll
    for (int j = 0; j < 16; ++j) acc[j] = fmaf(wgt, xlv[j], acc[j]);
    c0 = n0; c1 = n1; eac = ean;
  }

  float inv = 1.f / (l + 1e-16f);
  #pragma unroll
  for (int j = 0; j < 16; ++j) acc[j] *= inv;
  // sum the two heads: after xor both halves hold the head-pair sum
  #pragma unroll
  for (int j = 0; j < 16; ++j) acc[j] += __shfl_xor(acc[j], 32, 64);

  // full-wave layout: lane covers cols [cb + half*8, cb + half*8 + 8)
  float o[8];
  #pragma unroll
  for (int t = 0; t < 8; ++t) o[t] = half ? acc[8 + t] : acc[t];
  int colb = cb + half * 8;

  if (batch == 0) {
    float4* bp = (float4*)(B + (size_t)n * DD + colb);
    bp[0] = make_float4(o[0], o[1], o[2], o[3]);
    bp[1] = make_float4(o[4], o[5], o[6], o[7]);
    return;
  }
  // batch 1: mean over 4 heads, bias, relu, +res, LN, write bf16
  const float4* bp = (const float4*)(B + (size_t)n * DD + colb);
  float4 b0 = bp[0], b1 = bp[1];
  float pb[8] = {b0.x, b0.y, b0.z, b0.w, b1.x, b1.y, b1.z, b1.w};
  ushortx8 rv = *(const ushortx8*)(Xbf + (size_t)n * DD + colb);
  float v[8];
  float s = 0.f, sq = 0.f;
  #pragma unroll
  for (int t = 0; t < 8; ++t) {
    float g = (pb[t] + o[t]) * 0.25f + gbias[colb + t];
    float val = fmaxf(g, 0.f) + bf2f(rv[t]);
    v[t] = val;
    s += val; sq += val * val;
  }
  s = wave_allreduce_sum(s);
  sq = wave_allreduce_sum(sq);
  float mu = s * (1.f / DD);
  float var = sq * (1.f / DD) - mu * mu;
  float rstd = rsqrtf(var + 1e-5f);
  ushortx8 ob;
  #pragma unroll
  for (int t = 0; t < 8; ++t)
    ob[t] = f2bf(fmaf((v[t] - mu) * rstd, gamma[colb + t], beta[colb + t]));
  *(ushortx8*)(Xbf + (size_t)n * DD + colb) = ob;
}

// ---------------- GCN aggregate + fused bias/relu/res/LN ----------------
__global__ void k_dinv(const int* __restrict__ cnt, float* __restrict__ dinv) {
  int n = blockIdx.x * 256 + threadIdx.x;
  if (n < NN) dinv[n] = rsqrtf((float)cnt[n] + 1.0f);
}

__global__ void k_gcn_ln(const unsigned short* __restrict__ hw, const int* __restrict__ src,
                         const int* __restrict__ offs, const int* __restrict__ eids,
                         const float* __restrict__ dinv, const float* __restrict__ bias,
                         const float* __restrict__ gamma, const float* __restrict__ beta,
                         unsigned short* __restrict__ Xbf, float* __restrict__ outf) {
  int wave = (blockIdx.x * blockDim.x + threadIdx.x) >> 6;
  int lane = threadIdx.x & 63;
  if (wave >= NN) return;
  int n = wave;
  int cbase = lane * 8;
  float dn = dinv[n];
  float acc[8];
  {
    float wself = dn * dn;
    ushortx8 hv = *(const ushortx8*)(hw + (size_t)n * DD + cbase);
    #pragma unroll
    for (int j = 0; j < 8; ++j) acc[j] = wself * bf2f(hv[j]);
  }
  int beg = offs[n], end = offs[n + 1];
  int ecur = (beg < end) ? eids[beg] : 0;
  int scur = (beg < end) ? src[ecur] : 0;
  for (int p = beg; p < end; ++p) {
    int s = scur;
    if (p + 1 < end) { ecur = eids[p + 1]; scur = src[ecur]; }
    float wgt = dinv[s] * dn;
    ushortx8 hv = *(const ushortx8*)(hw + (size_t)s * DD + cbase);
    #pragma unroll
    for (int j = 0; j < 8; ++j) acc[j] = fmaf(wgt, bf2f(hv[j]), acc[j]);
  }
  ushortx8 rv = *(const ushortx8*)(Xbf + (size_t)n * DD + cbase);
  float v[8];
  float s = 0.f, sq = 0.f;
  #pragma unroll
  for (int j = 0; j < 8; ++j) {
    float g = acc[j] + bias[cbase + j];
    float t = fmaxf(g, 0.f) + bf2f(rv[j]);
    v[j] = t;
    s += t; sq += t * t;
  }
  s = wave_allreduce_sum(s);
  sq = wave_allreduce_sum(sq);
  float mu = s * (1.f / DD);
  float var = sq * (1.f / DD) - mu * mu;
  float rstd = rsqrtf(var + 1e-5f);
  if (outf) {
    float4* o4 = (float4*)(outf + (size_t)n * DD + cbase);
    float o[8];
    #pragma unroll
    for (int j = 0; j < 8; ++j)
      o[j] = fmaf((v[j] - mu) * rstd, gamma[cbase + j], beta[cbase + j]);
    o4[0] = make_float4(o[0], o[1], o[2], o[3]);
    o4[1] = make_float4(o[4], o[5], o[6], o[7]);
  } else {
    ushortx8 ob;
    #pragma unroll
    for (int j = 0; j < 8; ++j)
      ob[j] = f2bf(fmaf((v[j] - mu) * rstd, gamma[cbase + j], beta[cbase + j]));
    *(ushortx8*)(Xbf + (size_t)n * DD + cbase) = ob;
  }
}

// ---------------- host-side launcher ----------------
static void launch_bgemm(const unsigned short* A, const unsigned short* Bt,
                         const float* bias, void* C, int M, int Nc, int K,
                         int act, int outbf, hipStream_t stream) {
  dim3 grid(Nc / 128, M / 128);
  k_bgemm<<<grid, 256, 0, stream>>>(A, Bt, bias, C, M, Nc, K, act, outbf);
}

extern "C" void kernel_launch(void* const* d_in, const int* in_sizes, int n_in,
                              void* d_out, int out_size, void* d_ws, size_t ws_size,
                              hipStream_t stream) {
  const float* x       = (const float*)d_in[0];
  const int*   eidx    = (const int*)d_in[1];
  const float* eattr   = (const float*)d_in[2];
  const float* Wproj   = (const float*)d_in[3];
  const float* bproj   = (const float*)d_in[4];
  const float* geW     = (const float*)d_in[5];
  const float* geb     = (const float*)d_in[6];
  const float* gW1     = (const float*)d_in[7];
  const float* gb1     = (const float*)d_in[8];
  const float* gW2     = (const float*)d_in[9];
  const float* gb2     = (const float*)d_in[10];
  const float* gatWl   = (const float*)d_in[11];
  const float* gatbl   = (const float*)d_in[12];
  const float* gatWr   = (const float*)d_in[13];
  const float* gatbr   = (const float*)d_in[14];
  const float* gateW   = (const float*)d_in[15];
  const float* gatatt  = (const float*)d_in[16];
  const float* gatbias = (const float*)d_in[17];
  const float* gcn1W   = (const float*)d_in[18];
  const float* gcn1b   = (const float*)d_in[19];
  const float* gcn2W   = (const float*)d_in[20];
  const float* gcn2b   = (const float*)d_in[21];
  const float* lgamma  = (const float*)d_in[22];
  const float* lbeta   = (const float*)d_in[23];
  const int* srcArr = eidx;
  const int* dstArr = eidx + EE;

  // ---- workspace carving (~119 MB) ----
  char* p = (char*)d_ws;
  float* B            = (float*)p;          p += (size_t)NN * DD * 4;        // 32MB
  unsigned short* Xbf = (unsigned short*)p; p += (size_t)NN * DD * 2;        // 16MB
  unsigned short* U   = (unsigned short*)p; p += (size_t)NN * 2048 * 2;      // 64MB union
  unsigned short* w1t = (unsigned short*)p; p += (size_t)1024 * 512 * 2;
  unsigned short* w2t = (unsigned short*)p; p += (size_t)512 * 1024 * 2;
  unsigned short* wc0 = (unsigned short*)p; p += (size_t)2048 * 512 * 2;
  unsigned short* wc1 = (unsigned short*)p; p += (size_t)2048 * 512 * 2;
  unsigned short* g1t = (unsigned short*)p; p += (size_t)512 * 512 * 2;
  unsigned short* g2t = (unsigned short*)p; p += (size_t)512 * 512 * 2;
  float* bc0      = (float*)p;          p += 2048 * 4;
  float* bc1      = (float*)p;          p += 2048 * 4;
  float* macc     = (float*)p;          p += 4 * 4;
  float* dinv     = (float*)p;          p += (size_t)NN * 4;
  int*   cnt      = (int*)p;            p += (size_t)NN * 4;
  int*   offs     = (int*)p;            p += (size_t)(NN + 1) * 4 + 12;
  int*   cursor   = (int*)p;            p += (size_t)NN * 4;
  int*   eids     = (int*)p;            p += (size_t)EE * 4;

  unsigned short* Zbf = U;                    // NN x 512 (GINE agg out)
  unsigned short* Ybf = U + (size_t)NN * 512; // NN x 1024 (MLP mid)
  unsigned short* XLR = U;                    // NN x 2048 (GAT xl|xr, 2 heads)
  unsigned short* hw  = U;                    // NN x 512 (GCN h@W)

  hipMemsetAsync(cnt, 0, NN * sizeof(int), stream);
  hipMemsetAsync(cursor, 0, NN * sizeof(int), stream);
  hipMemsetAsync(macc, 0, 4 * sizeof(float), stream);

  k_count<<<EE / 256, 256, 0, stream>>>(dstArr, cnt);
  k_scan<<<1, 256, 0, stream>>>(cnt, offs);
  k_fill<<<EE / 256, 256, 0, stream>>>(dstArr, offs, cursor, eids);
  k_edge_mean<<<64, 256, 0, stream>>>(eattr, macc);

  // weight prep
  {
    k_transcast<<<dim3(1024 / 32, 512 / 32), 256, 0, stream>>>(gW1, 1024, w1t, 512, 1024);
    k_transcast<<<dim3(512 / 32, 1024 / 32), 256, 0, stream>>>(gW2, 512, w2t, 1024, 512);
    k_transcast<<<dim3(1024 / 32, 512 / 32), 256, 0, stream>>>(gatWl, 2048, wc0, 512, 1024);
    k_transcast<<<dim3(1024 / 32, 512 / 32), 256, 0, stream>>>(gatWr, 2048, wc0 + (size_t)1024 * 512, 512, 1024);
    k_transcast<<<dim3(1024 / 32, 512 / 32), 256, 0, stream>>>(gatWl + 1024, 2048, wc1, 512, 1024);
    k_transcast<<<dim3(1024 / 32, 512 / 32), 256, 0, stream>>>(gatWr + 1024, 2048, wc1 + (size_t)1024 * 512, 512, 1024);
    k_transcast<<<dim3(512 / 32, 512 / 32), 256, 0, stream>>>(gcn1W, 512, g1t, 512, 512);
    k_transcast<<<dim3(512 / 32, 512 / 32), 256, 0, stream>>>(gcn2W, 512, g2t, 512, 512);
    k_bcomb<<<16, 256, 0, stream>>>(gatbl, gatbr, bc0, bc1);
  }

  // input projection (bf16 only)
  k_proj<<<NN * DD / 256, 256, 0, stream>>>(x, Wproj, bproj, Xbf);

  // ---- layer 0: GINEConv + MLP + LN ----
  k_gine_agg<<<NN / 4, 256, 0, stream>>>(Xbf, srcArr, eattr, geW, geb, offs, eids, Zbf);
  launch_bgemm(Zbf, w1t, gb1, Ybf, NN, 1024, 512, 1, 1, stream);
  launch_bgemm(Ybf, w2t, gb2, B, NN, 512, 1024, 0, 0, stream);
  k_ln0<<<NN / 4, 256, 0, stream>>>(B, Xbf, lgamma, lbeta, Xbf);

  // ---- layer 1: GATv2, two 2-head batches, fused edge phase (indep. iterations) ----
  for (int b = 0; b < 2; ++b) {
    launch_bgemm(Xbf, b ? wc1 : wc0, b ? bc1 : bc0, XLR, NN, 2048, 512, 0, 1, stream);
    k_gat_fused<<<NN / 4, 256, 0, stream>>>(XLR, srcArr, offs, eids, eattr, macc,
                                            gateW, gatatt, B, Xbf, gatbias,
                                            lgamma + DD, lbeta + DD, b);
  }

  // ---- layers 2,3: GCN (aggregate + fused LN) ----
  k_dinv<<<NN / 256, 256, 0, stream>>>(cnt, dinv);
  launch_bgemm(Xbf, g1t, nullptr, hw, NN, 512, 512, 0, 1, stream);
  k_gcn_ln<<<NN / 4, 256, 0, stream>>>(hw, srcArr, offs, eids, dinv, gcn1b,
                                       lgamma + 2 * DD, lbeta + 2 * DD, Xbf, nullptr);
  launch_bgemm(Xbf, g2t, nullptr, hw, NN, 512, 512, 0, 1, stream);
  k_gcn_ln<<<NN / 4, 256, 0, stream>>>(hw, srcArr, offs, eids, dinv, gcn2b,
                                       lgamma + 3 * DD, lbeta + 3 * DD, Xbf, (float*)d_out);
}

// Round 6
// 630.909 us; speedup vs baseline: 1.6137x; 1.6137x over previous
//
#include <hip/hip_runtime.h>
#include <hip/hip_bf16.h>
#include <math.h>

#define NN   16384
#define EE   65536
#define DD   512
#define HH   4
#define FINN 7

typedef __attribute__((ext_vector_type(4))) float  floatx4;
typedef __attribute__((ext_vector_type(8))) float  floatx8;
typedef __attribute__((ext_vector_type(8))) short  shortx8;
typedef __attribute__((ext_vector_type(8))) unsigned short ushortx8;

// ---------------- helpers ----------------
__device__ inline float bf2f(unsigned short u) {
  return __uint_as_float(((unsigned)u) << 16);
}
__device__ inline unsigned short f2bf(float f) {
  unsigned u = __float_as_uint(f);
  unsigned r = (u + 0x7fffu + ((u >> 16) & 1u)) >> 16;
  return (unsigned short)r;
}
__device__ inline float wave_reduce_sum(float v) {
  #pragma unroll
  for (int off = 32; off > 0; off >>= 1) v += __shfl_down(v, off, 64);
  return v;
}
__device__ inline float wave_allreduce_sum(float v) {
  #pragma unroll
  for (int off = 32; off > 0; off >>= 1) v += __shfl_xor(v, off, 64);
  return v;
}
__device__ inline void async16(const unsigned short* g, unsigned short* l) {
  __builtin_amdgcn_global_load_lds(
      (const __attribute__((address_space(1))) void*)g,
      (__attribute__((address_space(3))) void*)l, 16, 0, 0);
}

// ---------------- CSR build ----------------
__global__ void k_count(const int* __restrict__ dst, int* __restrict__ cnt) {
  int e = blockIdx.x * 256 + threadIdx.x;
  if (e < EE) atomicAdd(&cnt[dst[e]], 1);
}

__global__ void k_scan(const int* __restrict__ cnt, int* __restrict__ offs) {
  __shared__ int sums[256];
  int t = threadIdx.x;
  const int chunk = NN / 256;
  int base = t * chunk;
  int s = 0;
  for (int i = 0; i < chunk; ++i) s += cnt[base + i];
  sums[t] = s;
  __syncthreads();
  for (int off = 1; off < 256; off <<= 1) {
    int v = (t >= off) ? sums[t - off] : 0;
    __syncthreads();
    sums[t] += v;
    __syncthreads();
  }
  int run = (t == 0) ? 0 : sums[t - 1];
  for (int i = 0; i < chunk; ++i) {
    offs[base + i] = run;
    run += cnt[base + i];
  }
  if (t == 255) offs[NN] = run;
}

__global__ void k_fill(const int* __restrict__ dst, const int* __restrict__ offs,
                       int* __restrict__ cursor, int* __restrict__ eids) {
  int e = blockIdx.x * 256 + threadIdx.x;
  if (e >= EE) return;
  int d = dst[e];
  int p = offs[d] + atomicAdd(&cursor[d], 1);
  eids[p] = e;
}

// ---------------- edge_attr mean ----------------
__global__ void k_edge_mean(const float* __restrict__ eattr, float* __restrict__ macc) {
  int tid = blockIdx.x * blockDim.x + threadIdx.x;
  int stride = gridDim.x * blockDim.x;
  float ax = 0.f, ay = 0.f, az = 0.f, aw = 0.f;
  for (int e = tid; e < EE; e += stride) {
    float4 v = ((const float4*)eattr)[e];
    ax += v.x; ay += v.y; az += v.z; aw += v.w;
  }
  ax = wave_reduce_sum(ax); ay = wave_reduce_sum(ay);
  az = wave_reduce_sum(az); aw = wave_reduce_sum(aw);
  if ((threadIdx.x & 63) == 0) {
    atomicAdd(&macc[0], ax); atomicAdd(&macc[1], ay);
    atomicAdd(&macc[2], az); atomicAdd(&macc[3], aw);
  }
}

// ------------- weight transpose+cast: W slice (K x N, ld) f32 -> Wt[N][K] bf16 -------
__global__ void k_transcast(const float* __restrict__ W, int ld,
                            unsigned short* __restrict__ Wt, int K, int N) {
  __shared__ float tile[32][33];
  int bx = blockIdx.x;
  int by = blockIdx.y;
  int tx = threadIdx.x & 31, ty = threadIdx.x >> 5;
  #pragma unroll
  for (int i = 0; i < 32; i += 8)
    tile[ty + i][tx] = W[(size_t)(by * 32 + ty + i) * ld + bx * 32 + tx];
  __syncthreads();
  #pragma unroll
  for (int i = 0; i < 32; i += 8)
    Wt[(size_t)(bx * 32 + ty + i) * K + by * 32 + tx] = f2bf(tile[tx][ty + i]);
}

// ------------- combined GAT bias ----------------
__global__ void k_bcomb(const float* __restrict__ bl, const float* __restrict__ br,
                        float* __restrict__ bc0, float* __restrict__ bc1) {
  int i = blockIdx.x * 256 + threadIdx.x;
  if (i >= 4096) return;
  int b = i >> 11, c = i & 2047;
  float v = (c < 1024) ? bl[b * 1024 + c] : br[b * 1024 + c - 1024];
  (b ? bc1 : bc0)[c] = v;
}

// ---------------- input projection ----------------
__global__ void k_proj(const float* __restrict__ x, const float* __restrict__ W,
                       const float* __restrict__ b, unsigned short* __restrict__ hbf) {
  int gid = blockIdx.x * 256 + threadIdx.x;
  if (gid >= NN * DD) return;
  int n = gid >> 9, d = gid & 511;
  const float* xr = x + n * FINN;
  float acc = b[d];
  #pragma unroll
  for (int k = 0; k < FINN; ++k) acc = fmaf(xr[k], W[k * DD + d], acc);
  hbf[gid] = f2bf(fmaxf(acc, 0.f));
}

// ---------------- bf16 MFMA GEMM with XOR-swizzled LDS ----------------
__global__ __launch_bounds__(256) void k_bgemm(
    const unsigned short* __restrict__ A, const unsigned short* __restrict__ Bt,
    const float* __restrict__ bias, void* __restrict__ Cout,
    int M, int Nc, int K, int act, int outbf) {
  __shared__ unsigned short As[128 * 64];
  __shared__ unsigned short Bs[128 * 64];
  const int tid = threadIdx.x;
  const int wv = tid >> 6;
  const int lane = tid & 63;
  const int row0 = blockIdx.y * 128;
  const int col0 = blockIdx.x * 128;
  const int wrow = (wv & 1) * 64;
  const int wcol = (wv >> 1) * 64;

  floatx4 acc[4][4];
  #pragma unroll
  for (int r = 0; r < 4; ++r)
    #pragma unroll
    for (int c = 0; c < 4; ++c)
      #pragma unroll
      for (int q = 0; q < 4; ++q) acc[r][c][q] = 0.f;

  const unsigned short* Ab = A + (size_t)row0 * K;
  const unsigned short* Bb = Bt + (size_t)col0 * K;
  const int lrow = lane >> 3;                       // 0..7 within segment
  const int lchunk = (lane & 7) ^ lrow;             // swizzled source k-chunk
  const int lk = lchunk * 8;                        // shorts

  const int frow = lane & 15;
  const int fx = lane >> 4;
  const int fsw = lane & 7;

  for (int k0 = 0; k0 < K; k0 += 64) {
    #pragma unroll
    for (int i = 0; i < 4; ++i) {
      int seg = i * 4 + wv;
      int r = seg * 8 + lrow;
      async16(Ab + (size_t)r * K + k0 + lk, &As[seg * 512]);
      async16(Bb + (size_t)r * K + k0 + lk, &Bs[seg * 512]);
    }
    __syncthreads();
    #pragma unroll
    for (int s = 0; s < 2; ++s) {
      int ch = ((s * 4 + fx) ^ fsw) * 8;
      shortx8 af[4], bfr[4];
      #pragma unroll
      for (int r = 0; r < 4; ++r)
        af[r] = *(const shortx8*)&As[(wrow + r * 16 + frow) * 64 + ch];
      #pragma unroll
      for (int c = 0; c < 4; ++c)
        bfr[c] = *(const shortx8*)&Bs[(wcol + c * 16 + frow) * 64 + ch];
      #pragma unroll
      for (int r = 0; r < 4; ++r)
        #pragma unroll
        for (int c = 0; c < 4; ++c)
          acc[r][c] = __builtin_amdgcn_mfma_f32_16x16x32_bf16(af[r], bfr[c], acc[r][c], 0, 0, 0);
    }
    __syncthreads();
  }

  #pragma unroll
  for (int r = 0; r < 4; ++r) {
    int rowb = row0 + wrow + r * 16 + (lane >> 4) * 4;
    #pragma unroll
    for (int c = 0; c < 4; ++c) {
      int col = col0 + wcol + c * 16 + (lane & 15);
      float bv = bias ? bias[col] : 0.f;
      #pragma unroll
      for (int q = 0; q < 4; ++q) {
        float v = acc[r][c][q] + bv;
        if (act) v = fmaxf(v, 0.f);
        if (outbf)
          ((unsigned short*)Cout)[(size_t)(rowb + q) * Nc + col] = f2bf(v);
        else
          ((float*)Cout)[(size_t)(rowb + q) * Nc + col] = v;
      }
    }
  }
}

// ------------- GINE aggregate ----------------
__global__ void k_gine_agg(const unsigned short* __restrict__ hbf,
                           const int* __restrict__ src, const float* __restrict__ eattr,
                           const float* __restrict__ geW, const float* __restrict__ geb,
                           const int* __restrict__ offs, const int* __restrict__ eids,
                           unsigned short* __restrict__ gbf) {
  int wave = (blockIdx.x * blockDim.x + threadIdx.x) >> 6;
  int lane = threadIdx.x & 63;
  if (wave >= NN) return;
  int n = wave;
  int cbase = lane * 8;
  floatx8 w0, w1, w2, w3, bb;
  #pragma unroll
  for (int j = 0; j < 8; ++j) {
    bb[j] = geb[cbase + j];
    w0[j] = geW[0 * DD + cbase + j];
    w1[j] = geW[1 * DD + cbase + j];
    w2[j] = geW[2 * DD + cbase + j];
    w3[j] = geW[3 * DD + cbase + j];
  }
  floatx8 acc = {0.f, 0.f, 0.f, 0.f, 0.f, 0.f, 0.f, 0.f};
  int beg = offs[n], end = offs[n + 1];
  int ecur = (beg < end) ? eids[beg] : 0;
  int scur = (beg < end) ? src[ecur] : 0;
  for (int p = beg; p < end; ++p) {
    int e = ecur, s = scur;
    if (p + 1 < end) { ecur = eids[p + 1]; scur = src[ecur]; }
    float4 ea = ((const float4*)eattr)[e];
    ushortx8 hv = *(const ushortx8*)(hbf + (size_t)s * DD + cbase);
    #pragma unroll
    for (int j = 0; j < 8; ++j) {
      float ev = bb[j];
      ev = fmaf(ea.x, w0[j], ev);
      ev = fmaf(ea.y, w1[j], ev);
      ev = fmaf(ea.z, w2[j], ev);
      ev = fmaf(ea.w, w3[j], ev);
      acc[j] += fmaxf(bf2f(hv[j]) + ev, 0.f);
    }
  }
  ushortx8 hn = *(const ushortx8*)(hbf + (size_t)n * DD + cbase);
  ushortx8 o;
  #pragma unroll
  for (int j = 0; j < 8; ++j) o[j] = f2bf(bf2f(hn[j]) + acc[j]);
  *(ushortx8*)(gbf + (size_t)n * DD + cbase) = o;
}

// -------- layer-0 LayerNorm ----------------
__global__ void k_ln0(const float* __restrict__ g, const unsigned short* __restrict__ res,
                      const float* __restrict__ gamma, const float* __restrict__ beta,
                      unsigned short* __restrict__ obf) {
  int wave = (blockIdx.x * blockDim.x + threadIdx.x) >> 6;
  int lane = threadIdx.x & 63;
  if (wave >= NN) return;
  int n = wave;
  int cbase = lane * 8;
  const float4* g4 = (const float4*)(g + (size_t)n * DD + cbase);
  ushortx8 rv = *(const ushortx8*)(res + (size_t)n * DD + cbase);
  float4 ga = g4[0], gb = g4[1];
  floatx8 v;
  v[0] = ga.x; v[1] = ga.y; v[2] = ga.z; v[3] = ga.w;
  v[4] = gb.x; v[5] = gb.y; v[6] = gb.z; v[7] = gb.w;
  float s = 0.f, sq = 0.f;
  #pragma unroll
  for (int j = 0; j < 8; ++j) {
    float t = fmaxf(v[j], 0.f) + bf2f(rv[j]);
    v[j] = t;
    s += t; sq += t * t;
  }
  s = wave_allreduce_sum(s);
  sq = wave_allreduce_sum(sq);
  float mu = s * (1.f / DD);
  float var = sq * (1.f / DD) - mu * mu;
  float rstd = rsqrtf(var + 1e-5f);
  ushortx8 ob;
  #pragma unroll
  for (int j = 0; j < 8; ++j)
    ob[j] = f2bf(fmaf((v[j] - mu) * rstd, gamma[cbase + j], beta[cbase + j]));
  *(ushortx8*)(obf + (size_t)n * DD + cbase) = ob;
}

// ======== fused GATv2: logits + direct-exp softmax + aggregate (+LN batch 1) ========
// wave per node; 2 heads per batch processed as TWO sequential full-wave loops
// (8 cols/lane over 64 lanes = 512 cols = one head). All per-lane state is in
// ext_vector SSA values -> cannot become allocas -> no scratch/LDS promotion
// (the r4/r5 killer: float w[4][16] spilled to scratch/LDS, LDS_Block_Size=65536).
__global__ __launch_bounds__(256) void k_gat_fused(
    const unsigned short* __restrict__ xlr,
    const int* __restrict__ src,
    const int* __restrict__ offs, const int* __restrict__ eids,
    const float* __restrict__ eattr, const float* __restrict__ macc,
    const float* __restrict__ geW /*4x2048*/,
    const float* __restrict__ att /*4x512 (HxC)*/,
    float* __restrict__ B, unsigned short* __restrict__ Xbf,
    const float* __restrict__ gbias,
    const float* __restrict__ gamma, const float* __restrict__ beta,
    int batch) {
  int wave = (blockIdx.x * blockDim.x + threadIdx.x) >> 6;
  int lane = threadIdx.x & 63;
  if (wave >= NN) return;
  int n = wave;
  int c8 = lane * 8;
  const float invE = 1.f / EE;
  float meax = macc[0] * invE, meay = macc[1] * invE;
  float meaz = macc[2] * invE, meaw = macc[3] * invE;
  int beg = offs[n], end = offs[n + 1];

  floatx8 accA = {0.f, 0.f, 0.f, 0.f, 0.f, 0.f, 0.f, 0.f};
  floatx8 accB = accA;

  #pragma unroll
  for (int h = 0; h < 2; ++h) {
    int hc = (2 * batch + h) * 512 + c8;   // column within H*C
    floatx8 w0, w1, w2, w3, atv, xrv;
    #pragma unroll
    for (int j = 0; j < 8; ++j) {
      w0[j] = geW[0 * (HH * DD) + hc + j];
      w1[j] = geW[1 * (HH * DD) + hc + j];
      w2[j] = geW[2 * (HH * DD) + hc + j];
      w3[j] = geW[3 * (HH * DD) + hc + j];
      atv[j] = att[hc + j];
    }
    {
      ushortx8 r = *(const ushortx8*)(xlr + (size_t)n * 2048 + 1024 + h * 512 + c8);
      #pragma unroll
      for (int j = 0; j < 8; ++j) xrv[j] = bf2f(r[j]);
    }
    float l;
    floatx8 acc;
    // ---- self-loop (edge attr = mean) ----
    {
      ushortx8 a = *(const ushortx8*)(xlr + (size_t)n * 2048 + h * 512 + c8);
      floatx8 xlv;
      float zacc = 0.f;
      #pragma unroll
      for (int j = 0; j < 8; ++j) {
        float xv = bf2f(a[j]);
        xlv[j] = xv;
        float z = xv + xrv[j];
        z = fmaf(meax, w0[j], z);
        z = fmaf(meay, w1[j], z);
        z = fmaf(meaz, w2[j], z);
        z = fmaf(meaw, w3[j], z);
        z = (z >= 0.f) ? z : 0.2f * z;
        zacc = fmaf(z, atv[j], zacc);
      }
      float L = wave_allreduce_sum(zacc);
      float wgt = __expf(L);
      l = wgt;
      #pragma unroll
      for (int j = 0; j < 8; ++j) acc[j] = wgt * xlv[j];
    }
    // ---- CSR edges (independent iterations; direct exp) ----
    int ecur = (beg < end) ? eids[beg] : 0;
    int scur = (beg < end) ? src[ecur] : 0;
    for (int p = beg; p < end; ++p) {
      int e = ecur, s = scur;
      if (p + 1 < end) { ecur = eids[p + 1]; scur = src[ecur]; }
      float4 ea = ((const float4*)eattr)[e];
      ushortx8 a = *(const ushortx8*)(xlr + (size_t)s * 2048 + h * 512 + c8);
      floatx8 xlv;
      float zacc = 0.f;
      #pragma unroll
      for (int j = 0; j < 8; ++j) {
        float xv = bf2f(a[j]);
        xlv[j] = xv;
        float z = xv + xrv[j];
        z = fmaf(ea.x, w0[j], z);
        z = fmaf(ea.y, w1[j], z);
        z = fmaf(ea.z, w2[j], z);
        z = fmaf(ea.w, w3[j], z);
        z = (z >= 0.f) ? z : 0.2f * z;
        zacc = fmaf(z, atv[j], zacc);
      }
      float L = wave_allreduce_sum(zacc);
      float wgt = __expf(L);
      l += wgt;
      #pragma unroll
      for (int j = 0; j < 8; ++j) acc[j] = fmaf(wgt, xlv[j], acc[j]);
    }
    float inv = 1.f / (l + 1e-16f);
    #pragma unroll
    for (int j = 0; j < 8; ++j) acc[j] *= inv;
    if (h == 0) accA = acc; else accB = acc;
  }

  floatx8 hsum = accA + accB;   // this batch's 2-head sum, cols c8..c8+8

  float* bp = B + (size_t)n * DD + c8;
  if (batch == 0) {
    float4 o0, o1;
    o0.x = hsum[0]; o0.y = hsum[1]; o0.z = hsum[2]; o0.w = hsum[3];
    o1.x = hsum[4]; o1.y = hsum[5]; o1.z = hsum[6]; o1.w = hsum[7];
    ((float4*)bp)[0] = o0;
    ((float4*)bp)[1] = o1;
    return;
  }
  // batch 1: mean over 4 heads, +bias, relu, +residual, LN, write bf16
  float4 b0 = ((const float4*)bp)[0];
  float4 b1 = ((const float4*)bp)[1];
  floatx8 prev;
  prev[0] = b0.x; prev[1] = b0.y; prev[2] = b0.z; prev[3] = b0.w;
  prev[4] = b1.x; prev[5] = b1.y; prev[6] = b1.z; prev[7] = b1.w;
  ushortx8 rv = *(const ushortx8*)(Xbf + (size_t)n * DD + c8);
  floatx8 v;
  float s = 0.f, sq = 0.f;
  #pragma unroll
  for (int j = 0; j < 8; ++j) {
    float g = (prev[j] + hsum[j]) * 0.25f + gbias[c8 + j];
    float val = fmaxf(g, 0.f) + bf2f(rv[j]);
    v[j] = val;
    s += val; sq += val * val;
  }
  s = wave_allreduce_sum(s);
  sq = wave_allreduce_sum(sq);
  float mu = s * (1.f / DD);
  float var = sq * (1.f / DD) - mu * mu;
  float rstd = rsqrtf(var + 1e-5f);
  ushortx8 ob;
  #pragma unroll
  for (int j = 0; j < 8; ++j)
    ob[j] = f2bf(fmaf((v[j] - mu) * rstd, gamma[c8 + j], beta[c8 + j]));
  *(ushortx8*)(Xbf + (size_t)n * DD + c8) = ob;
}

// ---------------- GCN aggregate + fused bias/relu/res/LN ----------------
__global__ void k_dinv(const int* __restrict__ cnt, float* __restrict__ dinv) {
  int n = blockIdx.x * 256 + threadIdx.x;
  if (n < NN) dinv[n] = rsqrtf((float)cnt[n] + 1.0f);
}

__global__ void k_gcn_ln(const unsigned short* __restrict__ hw, const int* __restrict__ src,
                         const int* __restrict__ offs, const int* __restrict__ eids,
                         const float* __restrict__ dinv, const float* __restrict__ bias,
                         const float* __restrict__ gamma, const float* __restrict__ beta,
                         unsigned short* __restrict__ Xbf, float* __restrict__ outf) {
  int wave = (blockIdx.x * blockDim.x + threadIdx.x) >> 6;
  int lane = threadIdx.x & 63;
  if (wave >= NN) return;
  int n = wave;
  int cbase = lane * 8;
  float dn = dinv[n];
  floatx8 acc;
  {
    float wself = dn * dn;
    ushortx8 hv = *(const ushortx8*)(hw + (size_t)n * DD + cbase);
    #pragma unroll
    for (int j = 0; j < 8; ++j) acc[j] = wself * bf2f(hv[j]);
  }
  int beg = offs[n], end = offs[n + 1];
  int ecur = (beg < end) ? eids[beg] : 0;
  int scur = (beg < end) ? src[ecur] : 0;
  for (int p = beg; p < end; ++p) {
    int s = scur;
    if (p + 1 < end) { ecur = eids[p + 1]; scur = src[ecur]; }
    float wgt = dinv[s] * dn;
    ushortx8 hv = *(const ushortx8*)(hw + (size_t)s * DD + cbase);
    #pragma unroll
    for (int j = 0; j < 8; ++j) acc[j] = fmaf(wgt, bf2f(hv[j]), acc[j]);
  }
  ushortx8 rv = *(const ushortx8*)(Xbf + (size_t)n * DD + cbase);
  floatx8 v;
  float s = 0.f, sq = 0.f;
  #pragma unroll
  for (int j = 0; j < 8; ++j) {
    float g = acc[j] + bias[cbase + j];
    float t = fmaxf(g, 0.f) + bf2f(rv[j]);
    v[j] = t;
    s += t; sq += t * t;
  }
  s = wave_allreduce_sum(s);
  sq = wave_allreduce_sum(sq);
  float mu = s * (1.f / DD);
  float var = sq * (1.f / DD) - mu * mu;
  float rstd = rsqrtf(var + 1e-5f);
  if (outf) {
    float4* o4 = (float4*)(outf + (size_t)n * DD + cbase);
    float4 oa, ob4;
    oa.x = fmaf((v[0] - mu) * rstd, gamma[cbase + 0], beta[cbase + 0]);
    oa.y = fmaf((v[1] - mu) * rstd, gamma[cbase + 1], beta[cbase + 1]);
    oa.z = fmaf((v[2] - mu) * rstd, gamma[cbase + 2], beta[cbase + 2]);
    oa.w = fmaf((v[3] - mu) * rstd, gamma[cbase + 3], beta[cbase + 3]);
    ob4.x = fmaf((v[4] - mu) * rstd, gamma[cbase + 4], beta[cbase + 4]);
    ob4.y = fmaf((v[5] - mu) * rstd, gamma[cbase + 5], beta[cbase + 5]);
    ob4.z = fmaf((v[6] - mu) * rstd, gamma[cbase + 6], beta[cbase + 6]);
    ob4.w = fmaf((v[7] - mu) * rstd, gamma[cbase + 7], beta[cbase + 7]);
    o4[0] = oa;
    o4[1] = ob4;
  } else {
    ushortx8 ob;
    #pragma unroll
    for (int j = 0; j < 8; ++j)
      ob[j] = f2bf(fmaf((v[j] - mu) * rstd, gamma[cbase + j], beta[cbase + j]));
    *(ushortx8*)(Xbf + (size_t)n * DD + cbase) = ob;
  }
}

// ---------------- host-side launcher ----------------
static void launch_bgemm(const unsigned short* A, const unsigned short* Bt,
                         const float* bias, void* C, int M, int Nc, int K,
                         int act, int outbf, hipStream_t stream) {
  dim3 grid(Nc / 128, M / 128);
  k_bgemm<<<grid, 256, 0, stream>>>(A, Bt, bias, C, M, Nc, K, act, outbf);
}

extern "C" void kernel_launch(void* const* d_in, const int* in_sizes, int n_in,
                              void* d_out, int out_size, void* d_ws, size_t ws_size,
                              hipStream_t stream) {
  const float* x       = (const float*)d_in[0];
  const int*   eidx    = (const int*)d_in[1];
  const float* eattr   = (const float*)d_in[2];
  const float* Wproj   = (const float*)d_in[3];
  const float* bproj   = (const float*)d_in[4];
  const float* geW     = (const float*)d_in[5];
  const float* geb     = (const float*)d_in[6];
  const float* gW1     = (const float*)d_in[7];
  const float* gb1     = (const float*)d_in[8];
  const float* gW2     = (const float*)d_in[9];
  const float* gb2     = (const float*)d_in[10];
  const float* gatWl   = (const float*)d_in[11];
  const float* gatbl   = (const float*)d_in[12];
  const float* gatWr   = (const float*)d_in[13];
  const float* gatbr   = (const float*)d_in[14];
  const float* gateW   = (const float*)d_in[15];
  const float* gatatt  = (const float*)d_in[16];
  const float* gatbias = (const float*)d_in[17];
  const float* gcn1W   = (const float*)d_in[18];
  const float* gcn1b   = (const float*)d_in[19];
  const float* gcn2W   = (const float*)d_in[20];
  const float* gcn2b   = (const float*)d_in[21];
  const float* lgamma  = (const float*)d_in[22];
  const float* lbeta   = (const float*)d_in[23];
  const int* srcArr = eidx;
  const int* dstArr = eidx + EE;

  // ---- workspace carving (~119 MB) ----
  char* p = (char*)d_ws;
  float* B            = (float*)p;          p += (size_t)NN * DD * 4;        // 32MB
  unsigned short* Xbf = (unsigned short*)p; p += (size_t)NN * DD * 2;        // 16MB
  unsigned short* U   = (unsigned short*)p; p += (size_t)NN * 2048 * 2;      // 64MB union
  unsigned short* w1t = (unsigned short*)p; p += (size_t)1024 * 512 * 2;
  unsigned short* w2t = (unsigned short*)p; p += (size_t)512 * 1024 * 2;
  unsigned short* wc0 = (unsigned short*)p; p += (size_t)2048 * 512 * 2;
  unsigned short* wc1 = (unsigned short*)p; p += (size_t)2048 * 512 * 2;
  unsigned short* g1t = (unsigned short*)p; p += (size_t)512 * 512 * 2;
  unsigned short* g2t = (unsigned short*)p; p += (size_t)512 * 512 * 2;
  float* bc0      = (float*)p;          p += 2048 * 4;
  float* bc1      = (float*)p;          p += 2048 * 4;
  float* macc     = (float*)p;          p += 4 * 4;
  float* dinv     = (float*)p;          p += (size_t)NN * 4;
  int*   cnt      = (int*)p;            p += (size_t)NN * 4;
  int*   offs     = (int*)p;            p += (size_t)(NN + 1) * 4 + 12;
  int*   cursor   = (int*)p;            p += (size_t)NN * 4;
  int*   eids     = (int*)p;            p += (size_t)EE * 4;

  unsigned short* Zbf = U;                    // NN x 512 (GINE agg out)
  unsigned short* Ybf = U + (size_t)NN * 512; // NN x 1024 (MLP mid)
  unsigned short* XLR = U;                    // NN x 2048 (GAT xl|xr, 2 heads)
  unsigned short* hw  = U;                    // NN x 512 (GCN h@W)

  hipMemsetAsync(cnt, 0, NN * sizeof(int), stream);
  hipMemsetAsync(cursor, 0, NN * sizeof(int), stream);
  hipMemsetAsync(macc, 0, 4 * sizeof(float), stream);

  k_count<<<EE / 256, 256, 0, stream>>>(dstArr, cnt);
  k_scan<<<1, 256, 0, stream>>>(cnt, offs);
  k_fill<<<EE / 256, 256, 0, stream>>>(dstArr, offs, cursor, eids);
  k_edge_mean<<<64, 256, 0, stream>>>(eattr, macc);

  // weight prep
  {
    k_transcast<<<dim3(1024 / 32, 512 / 32), 256, 0, stream>>>(gW1, 1024, w1t, 512, 1024);
    k_transcast<<<dim3(512 / 32, 1024 / 32), 256, 0, stream>>>(gW2, 512, w2t, 1024, 512);
    k_transcast<<<dim3(1024 / 32, 512 / 32), 256, 0, stream>>>(gatWl, 2048, wc0, 512, 1024);
    k_transcast<<<dim3(1024 / 32, 512 / 32), 256, 0, stream>>>(gatWr, 2048, wc0 + (size_t)1024 * 512, 512, 1024);
    k_transcast<<<dim3(1024 / 32, 512 / 32), 256, 0, stream>>>(gatWl + 1024, 2048, wc1, 512, 1024);
    k_transcast<<<dim3(1024 / 32, 512 / 32), 256, 0, stream>>>(gatWr + 1024, 2048, wc1 + (size_t)1024 * 512, 512, 1024);
    k_transcast<<<dim3(512 / 32, 512 / 32), 256, 0, stream>>>(gcn1W, 512, g1t, 512, 512);
    k_transcast<<<dim3(512 / 32, 512 / 32), 256, 0, stream>>>(gcn2W, 512, g2t, 512, 512);
    k_bcomb<<<16, 256, 0, stream>>>(gatbl, gatbr, bc0, bc1);
  }

  // input projection (bf16 only)
  k_proj<<<NN * DD / 256, 256, 0, stream>>>(x, Wproj, bproj, Xbf);

  // ---- layer 0: GINEConv + MLP + LN ----
  k_gine_agg<<<NN / 4, 256, 0, stream>>>(Xbf, srcArr, eattr, geW, geb, offs, eids, Zbf);
  launch_bgemm(Zbf, w1t, gb1, Ybf, NN, 1024, 512, 1, 1, stream);
  launch_bgemm(Ybf, w2t, gb2, B, NN, 512, 1024, 0, 0, stream);
  k_ln0<<<NN / 4, 256, 0, stream>>>(B, Xbf, lgamma, lbeta, Xbf);

  // ---- layer 1: GATv2, two 2-head batches, fused edge phase ----
  for (int b = 0; b < 2; ++b) {
    launch_bgemm(Xbf, b ? wc1 : wc0, b ? bc1 : bc0, XLR, NN, 2048, 512, 0, 1, stream);
    k_gat_fused<<<NN / 4, 256, 0, stream>>>(XLR, srcArr, offs, eids, eattr, macc,
                                            gateW, gatatt, B, Xbf, gatbias,
                                            lgamma + DD, lbeta + DD, b);
  }

  // ---- layers 2,3: GCN (aggregate + fused LN) ----
  k_dinv<<<NN / 256, 256, 0, stream>>>(cnt, dinv);
  launch_bgemm(Xbf, g1t, nullptr, hw, NN, 512, 512, 0, 1, stream);
  k_gcn_ln<<<NN / 4, 256, 0, stream>>>(hw, srcArr, offs, eids, dinv, gcn1b,
                                       lgamma + 2 * DD, lbeta + 2 * DD, Xbf, nullptr);
  launch_bgemm(Xbf, g2t, nullptr, hw, NN, 512, 512, 0, 1, stream);
  k_gcn_ln<<<NN / 4, 256, 0, stream>>>(hw, srcArr, offs, eids, dinv, gcn2b,
                                       lgamma + 3 * DD, lbeta + 3 * DD, Xbf, (float*)d_out);
}

// Round 7
// 622.028 us; speedup vs baseline: 1.6367x; 1.0143x over previous
//
#include <hip/hip_runtime.h>
#include <hip/hip_bf16.h>
#include <math.h>

#define NN   16384
#define EE   65536
#define DD   512
#define HH   4
#define FINN 7

typedef __attribute__((ext_vector_type(4))) float  floatx4;
typedef __attribute__((ext_vector_type(8))) float  floatx8;
typedef __attribute__((ext_vector_type(8))) short  shortx8;
typedef __attribute__((ext_vector_type(8))) unsigned short ushortx8;

// ---------------- helpers ----------------
__device__ inline float bf2f(unsigned short u) {
  return __uint_as_float(((unsigned)u) << 16);
}
__device__ inline unsigned short f2bf(float f) {
  unsigned u = __float_as_uint(f);
  unsigned r = (u + 0x7fffu + ((u >> 16) & 1u)) >> 16;
  return (unsigned short)r;
}
__device__ inline float wave_reduce_sum(float v) {
  #pragma unroll
  for (int off = 32; off > 0; off >>= 1) v += __shfl_down(v, off, 64);
  return v;
}
__device__ inline float wave_allreduce_sum(float v) {
  #pragma unroll
  for (int off = 32; off > 0; off >>= 1) v += __shfl_xor(v, off, 64);
  return v;
}
__device__ inline void async16(const unsigned short* g, unsigned short* l) {
  __builtin_amdgcn_global_load_lds(
      (const __attribute__((address_space(1))) void*)g,
      (__attribute__((address_space(3))) void*)l, 16, 0, 0);
}

// ---------------- CSR build ----------------
__global__ void k_count(const int* __restrict__ dst, int* __restrict__ cnt) {
  int e = blockIdx.x * 256 + threadIdx.x;
  if (e < EE) atomicAdd(&cnt[dst[e]], 1);
}

__global__ void k_scan(const int* __restrict__ cnt, int* __restrict__ offs) {
  __shared__ int sums[256];
  int t = threadIdx.x;
  const int chunk = NN / 256;
  int base = t * chunk;
  int s = 0;
  for (int i = 0; i < chunk; ++i) s += cnt[base + i];
  sums[t] = s;
  __syncthreads();
  for (int off = 1; off < 256; off <<= 1) {
    int v = (t >= off) ? sums[t - off] : 0;
    __syncthreads();
    sums[t] += v;
    __syncthreads();
  }
  int run = (t == 0) ? 0 : sums[t - 1];
  for (int i = 0; i < chunk; ++i) {
    offs[base + i] = run;
    run += cnt[base + i];
  }
  if (t == 255) offs[NN] = run;
}

__global__ void k_fill(const int* __restrict__ dst, const int* __restrict__ offs,
                       int* __restrict__ cursor, int* __restrict__ eids) {
  int e = blockIdx.x * 256 + threadIdx.x;
  if (e >= EE) return;
  int d = dst[e];
  int p = offs[d] + atomicAdd(&cursor[d], 1);
  eids[p] = e;
}

// ---------------- edge_attr mean ----------------
__global__ void k_edge_mean(const float* __restrict__ eattr, float* __restrict__ macc) {
  int tid = blockIdx.x * blockDim.x + threadIdx.x;
  int stride = gridDim.x * blockDim.x;
  float ax = 0.f, ay = 0.f, az = 0.f, aw = 0.f;
  for (int e = tid; e < EE; e += stride) {
    float4 v = ((const float4*)eattr)[e];
    ax += v.x; ay += v.y; az += v.z; aw += v.w;
  }
  ax = wave_reduce_sum(ax); ay = wave_reduce_sum(ay);
  az = wave_reduce_sum(az); aw = wave_reduce_sum(aw);
  if ((threadIdx.x & 63) == 0) {
    atomicAdd(&macc[0], ax); atomicAdd(&macc[1], ay);
    atomicAdd(&macc[2], az); atomicAdd(&macc[3], aw);
  }
}

// ------------- weight transpose+cast: W slice (K x N, ld) f32 -> Wt[N][K] bf16 -------
__global__ void k_transcast(const float* __restrict__ W, int ld,
                            unsigned short* __restrict__ Wt, int K, int N) {
  __shared__ float tile[32][33];
  int bx = blockIdx.x;
  int by = blockIdx.y;
  int tx = threadIdx.x & 31, ty = threadIdx.x >> 5;
  #pragma unroll
  for (int i = 0; i < 32; i += 8)
    tile[ty + i][tx] = W[(size_t)(by * 32 + ty + i) * ld + bx * 32 + tx];
  __syncthreads();
  #pragma unroll
  for (int i = 0; i < 32; i += 8)
    Wt[(size_t)(bx * 32 + ty + i) * K + by * 32 + tx] = f2bf(tile[tx][ty + i]);
}

// ------------- combined GAT bias ----------------
__global__ void k_bcomb(const float* __restrict__ bl, const float* __restrict__ br,
                        float* __restrict__ bc0, float* __restrict__ bc1) {
  int i = blockIdx.x * 256 + threadIdx.x;
  if (i >= 4096) return;
  int b = i >> 11, c = i & 2047;
  float v = (c < 1024) ? bl[b * 1024 + c] : br[b * 1024 + c - 1024];
  (b ? bc1 : bc0)[c] = v;
}

// ---------------- input projection ----------------
__global__ void k_proj(const float* __restrict__ x, const float* __restrict__ W,
                       const float* __restrict__ b, unsigned short* __restrict__ hbf) {
  int gid = blockIdx.x * 256 + threadIdx.x;
  if (gid >= NN * DD) return;
  int n = gid >> 9, d = gid & 511;
  const float* xr = x + n * FINN;
  float acc = b[d];
  #pragma unroll
  for (int k = 0; k < FINN; ++k) acc = fmaf(xr[k], W[k * DD + d], acc);
  hbf[gid] = f2bf(fmaxf(acc, 0.f));
}

// ---------------- bf16 MFMA GEMM with XOR-swizzled LDS ----------------
__global__ __launch_bounds__(256) void k_bgemm(
    const unsigned short* __restrict__ A, const unsigned short* __restrict__ Bt,
    const float* __restrict__ bias, void* __restrict__ Cout,
    int M, int Nc, int K, int act, int outbf) {
  __shared__ unsigned short As[128 * 64];
  __shared__ unsigned short Bs[128 * 64];
  const int tid = threadIdx.x;
  const int wv = tid >> 6;
  const int lane = tid & 63;
  const int row0 = blockIdx.y * 128;
  const int col0 = blockIdx.x * 128;
  const int wrow = (wv & 1) * 64;
  const int wcol = (wv >> 1) * 64;

  floatx4 acc[4][4];
  #pragma unroll
  for (int r = 0; r < 4; ++r)
    #pragma unroll
    for (int c = 0; c < 4; ++c)
      #pragma unroll
      for (int q = 0; q < 4; ++q) acc[r][c][q] = 0.f;

  const unsigned short* Ab = A + (size_t)row0 * K;
  const unsigned short* Bb = Bt + (size_t)col0 * K;
  const int lrow = lane >> 3;                       // 0..7 within segment
  const int lchunk = (lane & 7) ^ lrow;             // swizzled source k-chunk
  const int lk = lchunk * 8;                        // shorts

  const int frow = lane & 15;
  const int fx = lane >> 4;
  const int fsw = lane & 7;

  for (int k0 = 0; k0 < K; k0 += 64) {
    #pragma unroll
    for (int i = 0; i < 4; ++i) {
      int seg = i * 4 + wv;
      int r = seg * 8 + lrow;
      async16(Ab + (size_t)r * K + k0 + lk, &As[seg * 512]);
      async16(Bb + (size_t)r * K + k0 + lk, &Bs[seg * 512]);
    }
    __syncthreads();
    #pragma unroll
    for (int s = 0; s < 2; ++s) {
      int ch = ((s * 4 + fx) ^ fsw) * 8;
      shortx8 af[4], bfr[4];
      #pragma unroll
      for (int r = 0; r < 4; ++r)
        af[r] = *(const shortx8*)&As[(wrow + r * 16 + frow) * 64 + ch];
      #pragma unroll
      for (int c = 0; c < 4; ++c)
        bfr[c] = *(const shortx8*)&Bs[(wcol + c * 16 + frow) * 64 + ch];
      #pragma unroll
      for (int r = 0; r < 4; ++r)
        #pragma unroll
        for (int c = 0; c < 4; ++c)
          acc[r][c] = __builtin_amdgcn_mfma_f32_16x16x32_bf16(af[r], bfr[c], acc[r][c], 0, 0, 0);
    }
    __syncthreads();
  }

  #pragma unroll
  for (int r = 0; r < 4; ++r) {
    int rowb = row0 + wrow + r * 16 + (lane >> 4) * 4;
    #pragma unroll
    for (int c = 0; c < 4; ++c) {
      int col = col0 + wcol + c * 16 + (lane & 15);
      float bv = bias ? bias[col] : 0.f;
      #pragma unroll
      for (int q = 0; q < 4; ++q) {
        float v = acc[r][c][q] + bv;
        if (act) v = fmaxf(v, 0.f);
        if (outbf)
          ((unsigned short*)Cout)[(size_t)(rowb + q) * Nc + col] = f2bf(v);
        else
          ((float*)Cout)[(size_t)(rowb + q) * Nc + col] = v;
      }
    }
  }
}

// ------------- GINE aggregate ----------------
__global__ void k_gine_agg(const unsigned short* __restrict__ hbf,
                           const int* __restrict__ src, const float* __restrict__ eattr,
                           const float* __restrict__ geW, const float* __restrict__ geb,
                           const int* __restrict__ offs, const int* __restrict__ eids,
                           unsigned short* __restrict__ gbf) {
  int wave = (blockIdx.x * blockDim.x + threadIdx.x) >> 6;
  int lane = threadIdx.x & 63;
  if (wave >= NN) return;
  int n = wave;
  int cbase = lane * 8;
  floatx8 w0, w1, w2, w3, bb;
  #pragma unroll
  for (int j = 0; j < 8; ++j) {
    bb[j] = geb[cbase + j];
    w0[j] = geW[0 * DD + cbase + j];
    w1[j] = geW[1 * DD + cbase + j];
    w2[j] = geW[2 * DD + cbase + j];
    w3[j] = geW[3 * DD + cbase + j];
  }
  floatx8 acc = {0.f, 0.f, 0.f, 0.f, 0.f, 0.f, 0.f, 0.f};
  int beg = offs[n], end = offs[n + 1];
  int ecur = (beg < end) ? eids[beg] : 0;
  int scur = (beg < end) ? src[ecur] : 0;
  for (int p = beg; p < end; ++p) {
    int e = ecur, s = scur;
    if (p + 1 < end) { ecur = eids[p + 1]; scur = src[ecur]; }
    float4 ea = ((const float4*)eattr)[e];
    ushortx8 hv = *(const ushortx8*)(hbf + (size_t)s * DD + cbase);
    #pragma unroll
    for (int j = 0; j < 8; ++j) {
      float ev = bb[j];
      ev = fmaf(ea.x, w0[j], ev);
      ev = fmaf(ea.y, w1[j], ev);
      ev = fmaf(ea.z, w2[j], ev);
      ev = fmaf(ea.w, w3[j], ev);
      acc[j] += fmaxf(bf2f(hv[j]) + ev, 0.f);
    }
  }
  ushortx8 hn = *(const ushortx8*)(hbf + (size_t)n * DD + cbase);
  ushortx8 o;
  #pragma unroll
  for (int j = 0; j < 8; ++j) o[j] = f2bf(bf2f(hn[j]) + acc[j]);
  *(ushortx8*)(gbf + (size_t)n * DD + cbase) = o;
}

// -------- layer-0 LayerNorm ----------------
__global__ void k_ln0(const float* __restrict__ g, const unsigned short* __restrict__ res,
                      const float* __restrict__ gamma, const float* __restrict__ beta,
                      unsigned short* __restrict__ obf) {
  int wave = (blockIdx.x * blockDim.x + threadIdx.x) >> 6;
  int lane = threadIdx.x & 63;
  if (wave >= NN) return;
  int n = wave;
  int cbase = lane * 8;
  const float4* g4 = (const float4*)(g + (size_t)n * DD + cbase);
  ushortx8 rv = *(const ushortx8*)(res + (size_t)n * DD + cbase);
  float4 ga = g4[0], gb = g4[1];
  floatx8 v;
  v[0] = ga.x; v[1] = ga.y; v[2] = ga.z; v[3] = ga.w;
  v[4] = gb.x; v[5] = gb.y; v[6] = gb.z; v[7] = gb.w;
  float s = 0.f, sq = 0.f;
  #pragma unroll
  for (int j = 0; j < 8; ++j) {
    float t = fmaxf(v[j], 0.f) + bf2f(rv[j]);
    v[j] = t;
    s += t; sq += t * t;
  }
  s = wave_allreduce_sum(s);
  sq = wave_allreduce_sum(sq);
  float mu = s * (1.f / DD);
  float var = sq * (1.f / DD) - mu * mu;
  float rstd = rsqrtf(var + 1e-5f);
  ushortx8 ob;
  #pragma unroll
  for (int j = 0; j < 8; ++j)
    ob[j] = f2bf(fmaf((v[j] - mu) * rstd, gamma[cbase + j], beta[cbase + j]));
  *(ushortx8*)(obf + (size_t)n * DD + cbase) = ob;
}

// ======== fused GATv2: logits + direct-exp softmax + aggregate (+LN batch 1) ========
// wave per node; BOTH heads of the batch processed in a SINGLE edge pass:
// per edge, two independent 16B row loads (head0 at +0, head1 at +512), two
// interleaved shuffle-reduce chains (2x ILP), two accumulators. Halves edge
// iterations and index/eattr traffic vs the r6 two-pass version (latency-bound
// at 78us: VALU 37%, HBM 23%). All state in ext_vector SSA (no allocas).
__global__ __launch_bounds__(256) void k_gat_fused(
    const unsigned short* __restrict__ xlr,
    const int* __restrict__ src,
    const int* __restrict__ offs, const int* __restrict__ eids,
    const float* __restrict__ eattr, const float* __restrict__ macc,
    const float* __restrict__ geW /*4x2048*/,
    const float* __restrict__ att /*4x512 (HxC)*/,
    float* __restrict__ B, unsigned short* __restrict__ Xbf,
    const float* __restrict__ gbias,
    const float* __restrict__ gamma, const float* __restrict__ beta,
    int batch) {
  int wave = (blockIdx.x * blockDim.x + threadIdx.x) >> 6;
  int lane = threadIdx.x & 63;
  if (wave >= NN) return;
  int n = wave;
  int c8 = lane * 8;
  const float invE = 1.f / EE;
  float meax = macc[0] * invE, meay = macc[1] * invE;
  float meaz = macc[2] * invE, meaw = macc[3] * invE;
  int beg = offs[n], end = offs[n + 1];

  // per-head constants (head A = 2*batch, head B = 2*batch+1)
  int hcA = (2 * batch) * 512 + c8;
  int hcB = hcA + 512;
  floatx8 w0A, w1A, w2A, w3A, atA, xrA;
  floatx8 w0B, w1B, w2B, w3B, atB, xrB;
  #pragma unroll
  for (int j = 0; j < 8; ++j) {
    w0A[j] = geW[0 * (HH * DD) + hcA + j];
    w1A[j] = geW[1 * (HH * DD) + hcA + j];
    w2A[j] = geW[2 * (HH * DD) + hcA + j];
    w3A[j] = geW[3 * (HH * DD) + hcA + j];
    atA[j] = att[hcA + j];
    w0B[j] = geW[0 * (HH * DD) + hcB + j];
    w1B[j] = geW[1 * (HH * DD) + hcB + j];
    w2B[j] = geW[2 * (HH * DD) + hcB + j];
    w3B[j] = geW[3 * (HH * DD) + hcB + j];
    atB[j] = att[hcB + j];
  }
  {
    ushortx8 rA = *(const ushortx8*)(xlr + (size_t)n * 2048 + 1024 + c8);
    ushortx8 rB = *(const ushortx8*)(xlr + (size_t)n * 2048 + 1536 + c8);
    #pragma unroll
    for (int j = 0; j < 8; ++j) { xrA[j] = bf2f(rA[j]); xrB[j] = bf2f(rB[j]); }
  }

  float lA, lB;
  floatx8 accA, accB;
  // ---- self-loop (edge attr = mean) ----
  {
    ushortx8 aA = *(const ushortx8*)(xlr + (size_t)n * 2048 + c8);
    ushortx8 aB = *(const ushortx8*)(xlr + (size_t)n * 2048 + 512 + c8);
    floatx8 xA, xB;
    float zA = 0.f, zB = 0.f;
    #pragma unroll
    for (int j = 0; j < 8; ++j) {
      float vA = bf2f(aA[j]), vB = bf2f(aB[j]);
      xA[j] = vA; xB[j] = vB;
      float tA = vA + xrA[j];
      tA = fmaf(meax, w0A[j], tA);
      tA = fmaf(meay, w1A[j], tA);
      tA = fmaf(meaz, w2A[j], tA);
      tA = fmaf(meaw, w3A[j], tA);
      tA = (tA >= 0.f) ? tA : 0.2f * tA;
      zA = fmaf(tA, atA[j], zA);
      float tB = vB + xrB[j];
      tB = fmaf(meax, w0B[j], tB);
      tB = fmaf(meay, w1B[j], tB);
      tB = fmaf(meaz, w2B[j], tB);
      tB = fmaf(meaw, w3B[j], tB);
      tB = (tB >= 0.f) ? tB : 0.2f * tB;
      zB = fmaf(tB, atB[j], zB);
    }
    #pragma unroll
    for (int off = 32; off > 0; off >>= 1) {
      zA += __shfl_xor(zA, off, 64);
      zB += __shfl_xor(zB, off, 64);
    }
    float wA = __expf(zA), wB = __expf(zB);
    lA = wA; lB = wB;
    #pragma unroll
    for (int j = 0; j < 8; ++j) { accA[j] = wA * xA[j]; accB[j] = wB * xB[j]; }
  }
  // ---- CSR edges (single pass over edge list, both heads) ----
  int ecur = (beg < end) ? eids[beg] : 0;
  int scur = (beg < end) ? src[ecur] : 0;
  for (int p = beg; p < end; ++p) {
    int e = ecur, s = scur;
    if (p + 1 < end) { ecur = eids[p + 1]; scur = src[ecur]; }
    float4 ea = ((const float4*)eattr)[e];
    const unsigned short* xs = xlr + (size_t)s * 2048 + c8;
    ushortx8 aA = *(const ushortx8*)xs;
    ushortx8 aB = *(const ushortx8*)(xs + 512);
    floatx8 xA, xB;
    float zA = 0.f, zB = 0.f;
    #pragma unroll
    for (int j = 0; j < 8; ++j) {
      float vA = bf2f(aA[j]), vB = bf2f(aB[j]);
      xA[j] = vA; xB[j] = vB;
      float tA = vA + xrA[j];
      tA = fmaf(ea.x, w0A[j], tA);
      tA = fmaf(ea.y, w1A[j], tA);
      tA = fmaf(ea.z, w2A[j], tA);
      tA = fmaf(ea.w, w3A[j], tA);
      tA = (tA >= 0.f) ? tA : 0.2f * tA;
      zA = fmaf(tA, atA[j], zA);
      float tB = vB + xrB[j];
      tB = fmaf(ea.x, w0B[j], tB);
      tB = fmaf(ea.y, w1B[j], tB);
      tB = fmaf(ea.z, w2B[j], tB);
      tB = fmaf(ea.w, w3B[j], tB);
      tB = (tB >= 0.f) ? tB : 0.2f * tB;
      zB = fmaf(tB, atB[j], zB);
    }
    #pragma unroll
    for (int off = 32; off > 0; off >>= 1) {
      zA += __shfl_xor(zA, off, 64);
      zB += __shfl_xor(zB, off, 64);
    }
    float wA = __expf(zA), wB = __expf(zB);
    lA += wA; lB += wB;
    #pragma unroll
    for (int j = 0; j < 8; ++j) {
      accA[j] = fmaf(wA, xA[j], accA[j]);
      accB[j] = fmaf(wB, xB[j], accB[j]);
    }
  }

  float invA = 1.f / (lA + 1e-16f);
  float invB = 1.f / (lB + 1e-16f);
  floatx8 hsum;
  #pragma unroll
  for (int j = 0; j < 8; ++j) hsum[j] = accA[j] * invA + accB[j] * invB;

  float* bp = B + (size_t)n * DD + c8;
  if (batch == 0) {
    float4 o0, o1;
    o0.x = hsum[0]; o0.y = hsum[1]; o0.z = hsum[2]; o0.w = hsum[3];
    o1.x = hsum[4]; o1.y = hsum[5]; o1.z = hsum[6]; o1.w = hsum[7];
    ((float4*)bp)[0] = o0;
    ((float4*)bp)[1] = o1;
    return;
  }
  // batch 1: mean over 4 heads, +bias, relu, +residual, LN, write bf16
  float4 b0 = ((const float4*)bp)[0];
  float4 b1 = ((const float4*)bp)[1];
  floatx8 prev;
  prev[0] = b0.x; prev[1] = b0.y; prev[2] = b0.z; prev[3] = b0.w;
  prev[4] = b1.x; prev[5] = b1.y; prev[6] = b1.z; prev[7] = b1.w;
  ushortx8 rv = *(const ushortx8*)(Xbf + (size_t)n * DD + c8);
  floatx8 v;
  float s = 0.f, sq = 0.f;
  #pragma unroll
  for (int j = 0; j < 8; ++j) {
    float g = (prev[j] + hsum[j]) * 0.25f + gbias[c8 + j];
    float val = fmaxf(g, 0.f) + bf2f(rv[j]);
    v[j] = val;
    s += val; sq += val * val;
  }
  s = wave_allreduce_sum(s);
  sq = wave_allreduce_sum(sq);
  float mu = s * (1.f / DD);
  float var = sq * (1.f / DD) - mu * mu;
  float rstd = rsqrtf(var + 1e-5f);
  ushortx8 ob;
  #pragma unroll
  for (int j = 0; j < 8; ++j)
    ob[j] = f2bf(fmaf((v[j] - mu) * rstd, gamma[c8 + j], beta[c8 + j]));
  *(ushortx8*)(Xbf + (size_t)n * DD + c8) = ob;
}

// ---------------- GCN aggregate + fused bias/relu/res/LN ----------------
__global__ void k_dinv(const int* __restrict__ cnt, float* __restrict__ dinv) {
  int n = blockIdx.x * 256 + threadIdx.x;
  if (n < NN) dinv[n] = rsqrtf((float)cnt[n] + 1.0f);
}

__global__ void k_gcn_ln(const unsigned short* __restrict__ hw, const int* __restrict__ src,
                         const int* __restrict__ offs, const int* __restrict__ eids,
                         const float* __restrict__ dinv, const float* __restrict__ bias,
                         const float* __restrict__ gamma, const float* __restrict__ beta,
                         unsigned short* __restrict__ Xbf, float* __restrict__ outf) {
  int wave = (blockIdx.x * blockDim.x + threadIdx.x) >> 6;
  int lane = threadIdx.x & 63;
  if (wave >= NN) return;
  int n = wave;
  int cbase = lane * 8;
  float dn = dinv[n];
  floatx8 acc;
  {
    float wself = dn * dn;
    ushortx8 hv = *(const ushortx8*)(hw + (size_t)n * DD + cbase);
    #pragma unroll
    for (int j = 0; j < 8; ++j) acc[j] = wself * bf2f(hv[j]);
  }
  int beg = offs[n], end = offs[n + 1];
  int ecur = (beg < end) ? eids[beg] : 0;
  int scur = (beg < end) ? src[ecur] : 0;
  for (int p = beg; p < end; ++p) {
    int s = scur;
    if (p + 1 < end) { ecur = eids[p + 1]; scur = src[ecur]; }
    float wgt = dinv[s] * dn;
    ushortx8 hv = *(const ushortx8*)(hw + (size_t)s * DD + cbase);
    #pragma unroll
    for (int j = 0; j < 8; ++j) acc[j] = fmaf(wgt, bf2f(hv[j]), acc[j]);
  }
  ushortx8 rv = *(const ushortx8*)(Xbf + (size_t)n * DD + cbase);
  floatx8 v;
  float s = 0.f, sq = 0.f;
  #pragma unroll
  for (int j = 0; j < 8; ++j) {
    float g = acc[j] + bias[cbase + j];
    float t = fmaxf(g, 0.f) + bf2f(rv[j]);
    v[j] = t;
    s += t; sq += t * t;
  }
  s = wave_allreduce_sum(s);
  sq = wave_allreduce_sum(sq);
  float mu = s * (1.f / DD);
  float var = sq * (1.f / DD) - mu * mu;
  float rstd = rsqrtf(var + 1e-5f);
  if (outf) {
    float4* o4 = (float4*)(outf + (size_t)n * DD + cbase);
    float4 oa, ob4;
    oa.x = fmaf((v[0] - mu) * rstd, gamma[cbase + 0], beta[cbase + 0]);
    oa.y = fmaf((v[1] - mu) * rstd, gamma[cbase + 1], beta[cbase + 1]);
    oa.z = fmaf((v[2] - mu) * rstd, gamma[cbase + 2], beta[cbase + 2]);
    oa.w = fmaf((v[3] - mu) * rstd, gamma[cbase + 3], beta[cbase + 3]);
    ob4.x = fmaf((v[4] - mu) * rstd, gamma[cbase + 4], beta[cbase + 4]);
    ob4.y = fmaf((v[5] - mu) * rstd, gamma[cbase + 5], beta[cbase + 5]);
    ob4.z = fmaf((v[6] - mu) * rstd, gamma[cbase + 6], beta[cbase + 6]);
    ob4.w = fmaf((v[7] - mu) * rstd, gamma[cbase + 7], beta[cbase + 7]);
    o4[0] = oa;
    o4[1] = ob4;
  } else {
    ushortx8 ob;
    #pragma unroll
    for (int j = 0; j < 8; ++j)
      ob[j] = f2bf(fmaf((v[j] - mu) * rstd, gamma[cbase + j], beta[cbase + j]));
    *(ushortx8*)(Xbf + (size_t)n * DD + cbase) = ob;
  }
}

// ---------------- host-side launcher ----------------
static void launch_bgemm(const unsigned short* A, const unsigned short* Bt,
                         const float* bias, void* C, int M, int Nc, int K,
                         int act, int outbf, hipStream_t stream) {
  dim3 grid(Nc / 128, M / 128);
  k_bgemm<<<grid, 256, 0, stream>>>(A, Bt, bias, C, M, Nc, K, act, outbf);
}

extern "C" void kernel_launch(void* const* d_in, const int* in_sizes, int n_in,
                              void* d_out, int out_size, void* d_ws, size_t ws_size,
                              hipStream_t stream) {
  const float* x       = (const float*)d_in[0];
  const int*   eidx    = (const int*)d_in[1];
  const float* eattr   = (const float*)d_in[2];
  const float* Wproj   = (const float*)d_in[3];
  const float* bproj   = (const float*)d_in[4];
  const float* geW     = (const float*)d_in[5];
  const float* geb     = (const float*)d_in[6];
  const float* gW1     = (const float*)d_in[7];
  const float* gb1     = (const float*)d_in[8];
  const float* gW2     = (const float*)d_in[9];
  const float* gb2     = (const float*)d_in[10];
  const float* gatWl   = (const float*)d_in[11];
  const float* gatbl   = (const float*)d_in[12];
  const float* gatWr   = (const float*)d_in[13];
  const float* gatbr   = (const float*)d_in[14];
  const float* gateW   = (const float*)d_in[15];
  const float* gatatt  = (const float*)d_in[16];
  const float* gatbias = (const float*)d_in[17];
  const float* gcn1W   = (const float*)d_in[18];
  const float* gcn1b   = (const float*)d_in[19];
  const float* gcn2W   = (const float*)d_in[20];
  const float* gcn2b   = (const float*)d_in[21];
  const float* lgamma  = (const float*)d_in[22];
  const float* lbeta   = (const float*)d_in[23];
  const int* srcArr = eidx;
  const int* dstArr = eidx + EE;

  // ---- workspace carving (~119 MB) ----
  char* p = (char*)d_ws;
  float* B            = (float*)p;          p += (size_t)NN * DD * 4;        // 32MB
  unsigned short* Xbf = (unsigned short*)p; p += (size_t)NN * DD * 2;        // 16MB
  unsigned short* U   = (unsigned short*)p; p += (size_t)NN * 2048 * 2;      // 64MB union
  unsigned short* w1t = (unsigned short*)p; p += (size_t)1024 * 512 * 2;
  unsigned short* w2t = (unsigned short*)p; p += (size_t)512 * 1024 * 2;
  unsigned short* wc0 = (unsigned short*)p; p += (size_t)2048 * 512 * 2;
  unsigned short* wc1 = (unsigned short*)p; p += (size_t)2048 * 512 * 2;
  unsigned short* g1t = (unsigned short*)p; p += (size_t)512 * 512 * 2;
  unsigned short* g2t = (unsigned short*)p; p += (size_t)512 * 512 * 2;
  float* bc0      = (float*)p;          p += 2048 * 4;
  float* bc1      = (float*)p;          p += 2048 * 4;
  float* macc     = (float*)p;          p += 4 * 4;
  float* dinv     = (float*)p;          p += (size_t)NN * 4;
  int*   cnt      = (int*)p;            p += (size_t)NN * 4;
  int*   offs     = (int*)p;            p += (size_t)(NN + 1) * 4 + 12;
  int*   cursor   = (int*)p;            p += (size_t)NN * 4;
  int*   eids     = (int*)p;            p += (size_t)EE * 4;

  unsigned short* Zbf = U;                    // NN x 512 (GINE agg out)
  unsigned short* Ybf = U + (size_t)NN * 512; // NN x 1024 (MLP mid)
  unsigned short* XLR = U;                    // NN x 2048 (GAT xl|xr, 2 heads)
  unsigned short* hw  = U;                    // NN x 512 (GCN h@W)

  hipMemsetAsync(cnt, 0, NN * sizeof(int), stream);
  hipMemsetAsync(cursor, 0, NN * sizeof(int), stream);
  hipMemsetAsync(macc, 0, 4 * sizeof(float), stream);

  k_count<<<EE / 256, 256, 0, stream>>>(dstArr, cnt);
  k_scan<<<1, 256, 0, stream>>>(cnt, offs);
  k_fill<<<EE / 256, 256, 0, stream>>>(dstArr, offs, cursor, eids);
  k_edge_mean<<<64, 256, 0, stream>>>(eattr, macc);

  // weight prep
  {
    k_transcast<<<dim3(1024 / 32, 512 / 32), 256, 0, stream>>>(gW1, 1024, w1t, 512, 1024);
    k_transcast<<<dim3(512 / 32, 1024 / 32), 256, 0, stream>>>(gW2, 512, w2t, 1024, 512);
    k_transcast<<<dim3(1024 / 32, 512 / 32), 256, 0, stream>>>(gatWl, 2048, wc0, 512, 1024);
    k_transcast<<<dim3(1024 / 32, 512 / 32), 256, 0, stream>>>(gatWr, 2048, wc0 + (size_t)1024 * 512, 512, 1024);
    k_transcast<<<dim3(1024 / 32, 512 / 32), 256, 0, stream>>>(gatWl + 1024, 2048, wc1, 512, 1024);
    k_transcast<<<dim3(1024 / 32, 512 / 32), 256, 0, stream>>>(gatWr + 1024, 2048, wc1 + (size_t)1024 * 512, 512, 1024);
    k_transcast<<<dim3(512 / 32, 512 / 32), 256, 0, stream>>>(gcn1W, 512, g1t, 512, 512);
    k_transcast<<<dim3(512 / 32, 512 / 32), 256, 0, stream>>>(gcn2W, 512, g2t, 512, 512);
    k_bcomb<<<16, 256, 0, stream>>>(gatbl, gatbr, bc0, bc1);
  }

  // input projection (bf16 only)
  k_proj<<<NN * DD / 256, 256, 0, stream>>>(x, Wproj, bproj, Xbf);

  // ---- layer 0: GINEConv + MLP + LN ----
  k_gine_agg<<<NN / 4, 256, 0, stream>>>(Xbf, srcArr, eattr, geW, geb, offs, eids, Zbf);
  launch_bgemm(Zbf, w1t, gb1, Ybf, NN, 1024, 512, 1, 1, stream);
  launch_bgemm(Ybf, w2t, gb2, B, NN, 512, 1024, 0, 0, stream);
  k_ln0<<<NN / 4, 256, 0, stream>>>(B, Xbf, lgamma, lbeta, Xbf);

  // ---- layer 1: GATv2, two 2-head batches, fused single-pass edge phase ----
  for (int b = 0; b < 2; ++b) {
    launch_bgemm(Xbf, b ? wc1 : wc0, b ? bc1 : bc0, XLR, NN, 2048, 512, 0, 1, stream);
    k_gat_fused<<<NN / 4, 256, 0, stream>>>(XLR, srcArr, offs, eids, eattr, macc,
                                            gateW, gatatt, B, Xbf, gatbias,
                                            lgamma + DD, lbeta + DD, b);
  }

  // ---- layers 2,3: GCN (aggregate + fused LN) ----
  k_dinv<<<NN / 256, 256, 0, stream>>>(cnt, dinv);
  launch_bgemm(Xbf, g1t, nullptr, hw, NN, 512, 512, 0, 1, stream);
  k_gcn_ln<<<NN / 4, 256, 0, stream>>>(hw, srcArr, offs, eids, dinv, gcn1b,
                                       lgamma + 2 * DD, lbeta + 2 * DD, Xbf, nullptr);
  launch_bgemm(Xbf, g2t, nullptr, hw, NN, 512, 512, 0, 1, stream);
  k_gcn_ln<<<NN / 4, 256, 0, stream>>>(hw, srcArr, offs, eids, dinv, gcn2b,
                                       lgamma + 3 * DD, lbeta + 3 * DD, Xbf, (float*)d_out);
}